// Round 1
// 300.720 us; speedup vs baseline: 1.0623x; 1.0623x over previous
//
#include <hip/hip_runtime.h>
#include <stdint.h>

#define BDIM    512                   // 8 waves per batch
#define NROWS   32
#define CDIM    1024
#define NSTEPS  31
#define BATCH   512

// One 512-thread block (8 waves) per batch. ALL alive rows live in REGISTERS:
// wave w owns 4 "banks" k=0..3 holding slots s = w + 8k (STRIDED ownership so
// init work is balanced across waves); lane holds elements [lane*16..+15].
// Merged row overwrites slot sb's bank and D-row. The OTHER dead slot is
// idx[a] normally but idx[0] when a==1 (reference quirk) — kill THAT bank.
//
// Argmin is PARALLEL across all 512 threads and iterates SLOT pairs (s,t),
// t>s, over the fixed 32x32 domain: d2 = D[s][t] loads have NO dependent
// index indirection; tie-break key i*n+j (i<j) comes from posb[slot]->logical
// (127 = dead), maintained alongside nidx. Same (fp64 d2, flat) reference
// order as before -> bitwise-identical merge decisions.
//
// Init is SINGLE-PASS: stream each row once (1-deep register prefetch),
// owner wave captures it into R, all waves compute dist vs banks with s < i.
// Same per-lane accumulation order + butterfly as before -> bit-identical D.
// 3 barriers/step. No global reads after init.
__global__ __launch_bounds__(BDIM, 4)
void merge_tree_kernel(const float* __restrict__ xin,  // B*32*1024 fp32
                       const float* __restrict__ wz,   // 6 fp32 (1,2,3)
                       const float* __restrict__ bz,   // 1 fp32
                       float* __restrict__ out)        // B*1024 fp32
{
    const int b    = blockIdx.x;
    const int tid  = threadIdx.x;
    const int lane = tid & 63;
    const int wid  = tid >> 6;        // 0..7

    const float* xb = xin + (size_t)b * NROWS * CDIM;

    __shared__ double D[NROWS][NROWS + 1];   // slot-indexed d2 (8448 B)
    __shared__ float  mA[16 * 64];           // conv partial (ch0), [e][lane]
    __shared__ float  mB[16 * 64];           // conv partial (ch1), [e][lane]
    __shared__ int    idxbuf[2][NROWS];      // logical pos -> slot
    __shared__ int    posb[NROWS];           // slot -> logical pos, 127 = dead
    __shared__ int    bankSlot[32];          // bank (wid*4+k) -> slot, -1 dead
    __shared__ double wbk[8];                // per-wave argmin partial key
    __shared__ int    wbp[8];                // per-wave argmin partial flat

    const float w00 = wz[0], w01 = wz[1], w02 = wz[2];
    const float w10 = wz[3], w11 = wz[4], w12 = wz[5];
    const float cb  = bz[0];

    float R[4][16];                   // 4 owned rows (64 VGPRs)
    float m[16];                      // streamed / merged row
    float nxt[16];                    // init prefetch buffer

    if (tid < NROWS) {
        idxbuf[0][tid] = tid;
        posb[tid] = tid;
        // bank b = w*4+k  ->  slot w + 8k   (strided ownership)
        bankSlot[tid] = (tid >> 2) + ((tid & 3) << 3);
    }

    // ---------- single-pass init: stream row i, owner captures, dist vs s<i ----------
    {
        const float4* src = (const float4*)xb;    // row 0
        #pragma unroll
        for (int q = 0; q < 4; q++) {
            float4 t = src[lane * 4 + q];
            m[4*q] = t.x; m[4*q+1] = t.y; m[4*q+2] = t.z; m[4*q+3] = t.w;
        }
    }
    #pragma unroll 1
    for (int i = 0; i < NROWS; i++) {
        if (i < NROWS - 1) {                      // prefetch row i+1
            const float4* src = (const float4*)(xb + (size_t)(i + 1) * CDIM);
            #pragma unroll
            for (int q = 0; q < 4; q++) {
                float4 t = src[lane * 4 + q];
                nxt[4*q] = t.x; nxt[4*q+1] = t.y; nxt[4*q+2] = t.z; nxt[4*q+3] = t.w;
            }
        }
        double accv[4]; int sl[4];
        #pragma unroll
        for (int k = 0; k < 4; k++) {
            const int s = wid + (k << 3);         // strided slot, wave-uniform
            sl[k] = (s < i) ? s : -1;
            double acc = 0.0;
            if (s < i) {                          // wave-uniform
                #pragma unroll
                for (int e = 0; e < 16; e++) {
                    float d = m[e] - R[k][e];     // x_i - x_s (same order as before)
                    acc += (double)d * (double)d;
                }
            } else if (s == i) {                  // owner captures streamed row
                #pragma unroll
                for (int e = 0; e < 16; e++) R[k][e] = m[e];
            }
            accv[k] = acc;
        }
        #pragma unroll
        for (int k = 0; k < 4; k++) {
            if (sl[k] >= 0) {                     // wave-uniform
                double acc = accv[k];
                #pragma unroll
                for (int off = 32; off > 0; off >>= 1) acc += __shfl_down(acc, off, 64);
                if (lane == 0) { D[i][sl[k]] = acc; D[sl[k]][i] = acc; }
            }
        }
        if (i < NROWS - 1) {
            #pragma unroll
            for (int e = 0; e < 16; e++) m[e] = nxt[e];
        }
    }
    __syncthreads();

    // ---------- main merge loop: 3 barriers/step ----------
    int p = 0;
    #pragma unroll 1
    for (int step = 0; step < NSTEPS; step++) {
        const int n = NROWS - step;
        int* idx  = idxbuf[p];
        int* nidx = idxbuf[p ^ 1];
        const uint32_t M = 0xFFFFFFFFu / (uint32_t)n + 1u;  // exact for flat<2^27

        // --- parallel argmin over slot pairs, ALL 512 threads ---
        double bk = 1e300; int bp = 0x7fffffff;
        #pragma unroll
        for (int r = 0; r < (NROWS * NROWS) / BDIM; r++) {  // 2 iterations
            const int flat = r * BDIM + tid;
            const int s = flat >> 5, t = flat & 31;
            const int li = posb[s], lj = posb[t];           // independent LDS loads
            if (t > s && li < n && lj < n) {                // live pair, once
                double d2 = D[s][t];
                int fi = (li < lj) ? (li * n + lj) : (lj * n + li);
                if (d2 < bk || (d2 == bk && fi < bp)) { bk = d2; bp = fi; }
            }
        }
        #pragma unroll
        for (int off = 1; off < 64; off <<= 1) {
            double ov = __shfl_xor(bk, off, 64); int op = __shfl_xor(bp, off, 64);
            if (ov < bk || (ov == bk && op < bp)) { bk = ov; bp = op; }
        }
        if (lane == 0) { wbk[wid] = bk; wbp[wid] = bp; }
        __syncthreads();                                   // B1

        // --- final reduce of 8 partials, redundant on every thread (uniform) ---
        bk = wbk[0]; bp = wbp[0];
        #pragma unroll
        for (int w = 1; w < 8; w++) {
            double ov = wbk[w]; int op = wbp[w];
            if (ov < bk || (ov == bk && op < bp)) { bk = ov; bp = op; }
        }
        const int a   = (int)__umulhi((uint32_t)bp, M);
        const int bbj = bp - a * n;
        const int sa  = idx[a], sb = idx[bbj];
        // dead slots this step: sb is overwritten by merged; deadSlot dies
        const int deadSlot = (a == 1) ? idx[0] : sa;

        // --- conv partials by owner waves, from registers, into [e][lane] LDS ---
        #pragma unroll
        for (int k = 0; k < 4; k++) {
            const int s = bankSlot[wid * 4 + k];           // own entry, wave-uniform
            if (s == sa || s == sb) {
                float hl = __shfl_up(R[k][15], 1);  if (lane == 0)  hl = 0.0f;
                float hr = __shfl_down(R[k][0], 1); if (lane == 63) hr = 0.0f;
                float* dst = (s == sa) ? mA : mB;
                const float c0 = (s == sa) ? w00 : w10;
                const float c1 = (s == sa) ? w01 : w11;
                const float c2 = (s == sa) ? w02 : w12;
                #pragma unroll
                for (int e = 0; e < 16; e++) {
                    float xm1 = (e == 0)  ? hl : R[k][e - 1];
                    float xp1 = (e == 15) ? hr : R[k][e + 1];
                    dst[e * 64 + lane] = c0 * xm1 + c1 * R[k][e] + c2 * xp1;
                }
            }
        }
        // bookkeeping: new logical order (merged keeps slot id sb) + pos inverse
        if (tid == 0) { nidx[0] = sb; posb[sb] = 0; posb[deadSlot] = 127; }
        if (tid >= 1 && tid < n - 1) {
            int kk = tid + 1;
            int src = (kk == bbj) ? 1 : ((kk == a) ? 0 : kk);
            int sl2 = idx[src];
            nidx[tid] = sl2;
            posb[sl2] = tid;                               // survivors distinct; no race
        }
        __syncthreads();                                   // B2

        // --- finalize m (all waves need it); conflict-free strided reads ---
        #pragma unroll
        for (int e = 0; e < 16; e++) {
            float v = cb + mA[e * 64 + lane] + mB[e * 64 + lane];
            m[e] = v > 0.0f ? v : 0.0f;
        }
        // owner(sb): bank <- m; owner(deadSlot): kill bank; dists vs live banks
        double accv[4]; int sl[4];
        #pragma unroll
        for (int k = 0; k < 4; k++) {
            int s = bankSlot[wid * 4 + k];
            if (s == sb) {                                 // wave-uniform
                #pragma unroll
                for (int e = 0; e < 16; e++) R[k][e] = m[e];
            }
            if (s == deadSlot) {
                if (lane == 0) bankSlot[wid * 4 + k] = -1;
                s = -1;
            }
            const int live = (s >= 0 && s != sb) ? s : -1;
            sl[k] = live;
            double acc = 0.0;
            if (live >= 0) {                               // wave-uniform
                #pragma unroll
                for (int e = 0; e < 16; e++) {
                    float d = m[e] - R[k][e];
                    acc += (double)d * (double)d;
                }
            }
            accv[k] = acc;
        }
        #pragma unroll
        for (int k = 0; k < 4; k++) {
            if (sl[k] >= 0) {                              // wave-uniform
                double acc = accv[k];
                #pragma unroll
                for (int off = 32; off > 0; off >>= 1) acc += __shfl_down(acc, off, 64);
                if (lane == 0) { D[sb][sl[k]] = acc; D[sl[k]][sb] = acc; }
            }
        }
        __syncthreads();                                   // B3
        p ^= 1;
    }

    // final merged row is in m (all waves); wave 0 writes it
    if (wid == 0) {
        float4* od = (float4*)(out + (size_t)b * CDIM);
        #pragma unroll
        for (int q = 0; q < 4; q++)
            od[lane * 4 + q] = make_float4(m[4*q], m[4*q+1], m[4*q+2], m[4*q+3]);
    }
}

extern "C" void kernel_launch(void* const* d_in, const int* in_sizes, int n_in,
                              void* d_out, int out_size, void* d_ws, size_t ws_size,
                              hipStream_t stream) {
    const float* x  = (const float*)d_in[0]; // fp32 (512,32,1024)
    const float* w  = (const float*)d_in[1]; // fp32 (1,2,3)
    const float* cb = (const float*)d_in[2]; // fp32 (1,)
    float* out = (float*)d_out;              // fp32 (512,1024)
    (void)d_ws; (void)ws_size; (void)in_sizes; (void)n_in; (void)out_size;

    hipLaunchKernelGGL(merge_tree_kernel, dim3(BATCH), dim3(BDIM), 0, stream,
                       x, w, cb, out);
}